// Round 22
// baseline (102.984 us; speedup 1.0000x reference)
//
#include <hip/hip_runtime.h>
#include <hip/hip_bf16.h>
#include <stdint.h>

typedef __attribute__((ext_vector_type(8))) short short8;
typedef __attribute__((ext_vector_type(4))) float f32x4;
using bf16 = __hip_bfloat16;

#define MFMA16(a, b, c) __builtin_amdgcn_mfma_f32_16x16x32_bf16((a), (b), (c), 0, 0, 0)

#define GLOAD_LDS16(g, l) __builtin_amdgcn_global_load_lds( \
    (const __attribute__((address_space(1))) void*)(g),     \
    (__attribute__((address_space(3))) void*)(l), 16, 0, 0)

__device__ __forceinline__ unsigned packbf2(float lo, float hi) {
  unsigned r;
  asm("v_cvt_pk_bf16_f32 %0, %1, %2" : "=v"(r) : "v"(lo), "v"(hi));
  return r;
}
__device__ __forceinline__ float ex2(float x) {
  float r;
  asm("v_exp_f32 %0, %1" : "=v"(r) : "v"(x));
  return r;
}
__device__ __forceinline__ float bflo(unsigned a) {
  union { unsigned u; float f; } v; v.u = a << 16; return v.f;
}
__device__ __forceinline__ float bfhi(unsigned a) {
  union { unsigned u; float f; } v; v.u = a & 0xFFFF0000u; return v.f;
}

// pass-1: masked e1/e2, accumulate sums, optionally store packed (e1,e2) to P tile.
template <bool EDGE, bool STORE>
__device__ __forceinline__ void p1v(const f32x4* s1v, const f32x4* s2v,
                                    float& l1, float& l2,
                                    int kb0, int myq, int lhi, int qrow,
                                    unsigned* Pt) {
  float sum1 = 0.f, sum2 = 0.f;
#pragma unroll
  for (int nt = 0; nt < 4; ++nt) {
#pragma unroll
    for (int r = 0; r < 4; ++r) {
      float e1 = ex2(s1v[nt][r]);
      float e2 = ex2(s2v[nt][r]);
      if (EDGE) {
        int key = kb0 + nt * 16 + lhi * 4 + r;
        bool ok = (key <= myq) && (key > myq - 512);
        e1 = ok ? e1 : 0.f;
        e2 = ok ? e2 : 0.f;
      }
      sum1 += e1; sum2 += e2;
      if (STORE)
        Pt[(nt * 16 + lhi * 4 + r) * 64 + qrow] = packbf2(e1, e2);
    }
  }
  l1 += sum1; l2 += sum2;
}

// diagonal-tile pass-2 (recompute path)
template <bool EDGE>
__device__ __forceinline__ float p2s(const f32x4* s1v, const f32x4* s2v,
                                     float c2, int kb0, int myq, int lhi, int l15,
                                     unsigned* pw) {
  float d0 = 0.f, d1 = 0.f;
#pragma unroll
  for (int nt = 0; nt < 4; ++nt) {
    float pr[4];
#pragma unroll
    for (int r = 0; r < 4; ++r) {
      float e1 = ex2(s1v[nt][r]);
      float e2 = ex2(s2v[nt][r]);
      float p = fmaf(-c2, e2, e1);
      p = fmaxf(p, 0.f);
      if (EDGE) {
        int key = kb0 + nt * 16 + lhi * 4 + r;
        bool ok = (key <= myq) && (key > myq - 512);
        p = ok ? p : 0.f;
      }
      pr[r] = p;
      if (r & 1) d1 += p; else d0 += p;
    }
    int pi = l15 * 36 + 8 * nt + 2 * lhi;
    pw[pi]     = packbf2(pr[0], pr[1]);
    pw[pi + 1] = packbf2(pr[2], pr[3]);
  }
  return d0 + d1;
}

// ================= fused prep: x f32->bf16 row-major + weights -> FT bf16 =================
// Wq/Wk columns d-PERMUTED by swapping bits 5<->6 of d (self-inverse).
__global__ __launch_bounds__(256) void prep_all(const float* __restrict__ x,
                                                const float* __restrict__ Wq,
                                                const float* __restrict__ Wk,
                                                const float* __restrict__ Wv,
                                                const float* __restrict__ Wo,
                                                bf16* __restrict__ xb,
                                                bf16* __restrict__ WqkvFT,
                                                bf16* __restrict__ WoFT)
{
  const int bx = blockIdx.x;
  const int tid = threadIdx.x;
  if (bx >= 80) {
    size_t i = ((size_t)(bx - 80) * 32 + blockIdx.y) * 2048 + tid * 8;
    const float* f = x + i;
    float4 a = *(const float4*)f;
    float4 b = *(const float4*)(f + 4);
    union { bf16 h[8]; short8 s; } u;
    u.h[0] = __float2bfloat16(a.x); u.h[1] = __float2bfloat16(a.y);
    u.h[2] = __float2bfloat16(a.z); u.h[3] = __float2bfloat16(a.w);
    u.h[4] = __float2bfloat16(b.x); u.h[5] = __float2bfloat16(b.y);
    u.h[6] = __float2bfloat16(b.z); u.h[7] = __float2bfloat16(b.w);
    *(short8*)(xb + i) = u.s;
    return;
  }
  const float* W;
  bf16* Wt;
  int N, n0, prm;
  if (bx < 32)      { W = Wq; Wt = WqkvFT; N = 2048; n0 = bx * 64;               prm = 1; }
  else if (bx < 40) { W = Wk; Wt = WqkvFT; N = 512;  n0 = 2048 + (bx - 32) * 64; prm = 1; }
  else if (bx < 48) { W = Wv; Wt = WqkvFT; N = 512;  n0 = 2560 + (bx - 40) * 64; prm = 0; }
  else              { W = Wo; Wt = WoFT;   N = 2048; n0 = (bx - 48) * 64;        prm = 0; }
  const int nloc0 = (N == 512) ? (n0 - ((n0 >= 2560) ? 2560 : 2048)) : ((bx < 32 || bx >= 48) ? (n0 & 2047) : 0);
  const int k0 = blockIdx.y * 64;

  __shared__ bf16 t[64][72];
#pragma unroll
  for (int pass = 0; pass < 4; ++pass) {
    int r = pass * 16 + (tid >> 4);
    int c = (tid & 15) * 4;
    float4 v = *(const float4*)(W + (size_t)(k0 + r) * N + nloc0 + c);
    t[c + 0][r] = __float2bfloat16(v.x);
    t[c + 1][r] = __float2bfloat16(v.y);
    t[c + 2][r] = __float2bfloat16(v.z);
    t[c + 3][r] = __float2bfloat16(v.w);
  }
  __syncthreads();
#pragma unroll
  for (int pass = 0; pass < 2; ++pass) {
    int n = pass * 32 + (tid >> 3);
    int k8 = (tid & 7) * 8;
    int ng = n0 + n;
    if (prm) {
      int d = ng & 127;
      int dp = (d & 31) | ((d & 32) << 1) | ((d & 64) >> 1);
      ng = (ng & ~127) | dp;
    }
    int frag = (ng >> 4) * 64 + ((k0 + k8) >> 5);
    int ln = (ng & 15) + 16 * ((k8 >> 3) & 3);
    *(short8*)(Wt + (size_t)frag * 512 + ln * 8) = *(const short8*)(&t[n][k8]);
  }
}

// ================= QKV GEMM: 128x192 tile, 256 blocks, 8 waves (2m x 4n of 4x3) =================
__global__ __launch_bounds__(512) void gemm_qkv(const bf16* __restrict__ A,
                                                const bf16* __restrict__ Bft,
                                                bf16* __restrict__ QKV,
                                                bf16* __restrict__ VTp,
                                                int M, int N, int K)
{
  __shared__ __align__(16) char smem[65536];
  bf16* As = (bf16*)smem;

  const int tid  = threadIdx.x;
  const int lane = tid & 63;
  const int w    = tid >> 6;
  const int wmg  = (w >> 2) * 4;
  const int wn3  = (w & 3) * 3;
  const int l15  = lane & 15;
  const int lhi  = lane >> 4;

  const int nbx = gridDim.x;
  const int lb  = blockIdx.y * nbx + blockIdx.x;
  const int nwg = nbx * gridDim.y;
  const int lsw = (lb & 7) * (nwg >> 3) + (lb >> 3);
  const int bm0 = (lsw / nbx) * 128;
  const int bn0 = (lsw % nbx) * 192;

  const int srow = tid >> 2;
  const int scol = ((tid & 3) ^ ((tid >> 3) & 3)) * 8;
  const int loff = l15 * 4 + (lhi ^ ((l15 >> 1) & 3));

  const int nkc = K >> 5;
  const bf16* bbase[3];
#pragma unroll
  for (int nt = 0; nt < 3; ++nt)
    bbase[nt] = Bft + ((size_t)((bn0 >> 4) + wn3 + nt) * nkc) * 512 + lane * 8;

  f32x4 acc[4][3];
  const f32x4 zero4 = {0.f, 0.f, 0.f, 0.f};
#pragma unroll
  for (int i = 0; i < 4; ++i)
#pragma unroll
    for (int j = 0; j < 3; ++j) acc[i][j] = zero4;

  short8 br0[3], br1[3], br2[3], br3[3];

#define GSTAGE_A(buf, kk)                                                           \
  { GLOAD_LDS16(A + (size_t)(bm0 + srow) * K + (kk) + scol,                         \
                As + (buf) * 4096 + tid * 8); }

#define BLOAD(breg, kc)                                                             \
  { _Pragma("unroll")                                                               \
    for (int nt = 0; nt < 3; ++nt) {                                                \
      asm volatile("global_load_dwordx4 %0, %1, off"                                \
                   : "=v"(breg[nt])                                                 \
                   : "v"(bbase[nt] + (size_t)(kc) * 512)                            \
                   : "memory");                                                     \
    } }

#define KSTEP(aslot, breg, wcn, ...)                                                \
  {                                                                                 \
    asm volatile("s_waitcnt vmcnt(" #wcn ")" ::: "memory");                         \
    __builtin_amdgcn_s_barrier();                                                   \
    __builtin_amdgcn_sched_barrier(0);                                              \
    __VA_ARGS__                                                                     \
    short8 a_[4];                                                                   \
    _Pragma("unroll")                                                               \
    for (int mt = 0; mt < 4; ++mt)                                                  \
      a_[mt] = *(const short8*)(As + (aslot) * 4096 + ((wmg + mt) * 64 + loff) * 8);\
    _Pragma("unroll")                                                               \
    for (int mt = 0; mt < 4; ++mt)                                                  \
      _Pragma("unroll")                                                             \
      for (int nt = 0; nt < 3; ++nt)                                                \
        acc[mt][nt] = MFMA16(a_[mt], breg[nt], acc[mt][nt]);                        \
  }

  GSTAGE_A(0, 0);  BLOAD(br0, 0);
  GSTAGE_A(1, 32); BLOAD(br1, 1);
  GSTAGE_A(2, 64); BLOAD(br2, 2);

  for (int t = 0; t < nkc - 4; t += 4) {
    KSTEP(0, br0, 8, GSTAGE_A(3, (t + 3) * 32); BLOAD(br3, t + 3);)
    KSTEP(1, br1, 8, GSTAGE_A(0, (t + 4) * 32); BLOAD(br0, t + 4);)
    KSTEP(2, br2, 8, GSTAGE_A(1, (t + 5) * 32); BLOAD(br1, t + 5);)
    KSTEP(3, br3, 8, GSTAGE_A(2, (t + 6) * 32); BLOAD(br2, t + 6);)
  }
  KSTEP(0, br0, 8, GSTAGE_A(3, (nkc - 1) * 32); BLOAD(br3, nkc - 1);)
  KSTEP(1, br1, 8, )
  KSTEP(2, br2, 4, )
  KSTEP(3, br3, 0, )
#undef GSTAGE_A
#undef BLOAD
#undef KSTEP

  __syncthreads();

  const int ropeW = (bn0 + 192 <= 2560) ? 192 : ((bn0 >= 2560) ? 0 : 64);

  if (ropeW > 0) {
    float* Lf = (float*)smem;
#pragma unroll
    for (int half = 0; half < 2; ++half) {
      if ((w >> 2) == half) {
#pragma unroll
        for (int mt = 0; mt < 4; ++mt)
#pragma unroll
          for (int nt = 0; nt < 3; ++nt) {
            int lc = (wn3 + nt) * 16 + l15;
            if (lc < ropeW) {
#pragma unroll
              for (int r = 0; r < 4; ++r)
                Lf[(mt * 16 + lhi * 4 + r) * ropeW + lc] = acc[mt][nt][r];
            }
          }
      }
      __syncthreads();
      {
        int row = tid >> 3;
        int s = bm0 + half * 64 + row;
        if (ropeW == 192) {
          int cg = (tid & 7) * 24;
          bf16* orow = QKV + (size_t)s * 3072 + bn0 + cg;
          union { bf16 h[24]; short8 v[3]; } o;
#pragma unroll
          for (int e = 0; e < 24; ++e) {
            int c = cg + e;
            int g = bn0 + c;
            int p = g & 127;
            int w32 = p & 63;
            int b = p >> 6;
            int d = b * 32 + (w32 & 31);
            float scale = (g < 2048) ? 0.180336880111120f : 1.0f;
            float inv = __expf(-(float)d * (9.210340371976184f / 64.0f));
            float ang = (float)s * inv;
            float cs = __cosf(ang), sn = __sinf(ang);
            bool first = (w32 < 32);
            float xa = Lf[row * 192 + c];
            float xb2 = Lf[row * 192 + (first ? c + 32 : c - 32)];
            float out = fmaf(first ? -xb2 : xb2, sn, xa * cs);
            o.h[e] = __float2bfloat16(out * scale);
          }
          *(short8*)(orow)      = o.v[0];
          *(short8*)(orow + 8)  = o.v[1];
          *(short8*)(orow + 16) = o.v[2];
        } else {
          int cg = (tid & 7) * 8;
          bf16* orow = QKV + (size_t)s * 3072 + bn0 + cg;
          union { bf16 h[8]; short8 v; } o;
#pragma unroll
          for (int e = 0; e < 8; ++e) {
            int c = cg + e;
            int g = bn0 + c;
            int p = g & 127;
            int w32 = p & 63;
            int b = p >> 6;
            int d = b * 32 + (w32 & 31);
            float inv = __expf(-(float)d * (9.210340371976184f / 64.0f));
            float ang = (float)s * inv;
            float cs = __cosf(ang), sn = __sinf(ang);
            bool first = (w32 < 32);
            float xa = Lf[row * 64 + c];
            float xb2 = Lf[row * 64 + (first ? c + 32 : c - 32)];
            float out = fmaf(first ? -xb2 : xb2, sn, xa * cs);
            o.h[e] = __float2bfloat16(out);
          }
          *(short8*)(orow) = o.v;
        }
      }
      __syncthreads();
    }
  }
  if (bn0 + 192 > 2560) {
#pragma unroll
    for (int nt = 0; nt < 3; ++nt) {
      int gfc = bn0 + (wn3 + nt) * 16;
      if (gfc >= 2560) {
        int dim = gfc - 2560 + l15;
#pragma unroll
        for (int mt = 0; mt < 4; ++mt) {
          int key0 = bm0 + (w >> 2) * 64 + mt * 16 + lhi * 4;
          uint2 pk;
          pk.x = packbf2(acc[mt][nt][0], acc[mt][nt][1]);
          pk.y = packbf2(acc[mt][nt][2], acc[mt][nt][3]);
          *(uint2*)(VTp + (size_t)dim * 2048 + key0) = pk;
        }
      }
    }
  }
}

// ================= Wo GEMM: hybrid 128x128 =================
__global__ __launch_bounds__(256) void gemm_wo(const bf16* __restrict__ A,
                                               const bf16* __restrict__ Bft,
                                               float* __restrict__ C,
                                               int M, int N, int K)
{
  __shared__ __align__(16) bf16 As[4][128 * 32];

  const int tid  = threadIdx.x;
  const int lane = tid & 63;
  const int w    = tid >> 6;
  const int wmg  = (w >> 1) * 4;
  const int wng  = (w & 1) * 4;
  const int l15  = lane & 15;
  const int lhi  = lane >> 4;

  const int nbx = gridDim.x;
  const int lb  = blockIdx.y * nbx + blockIdx.x;
  const int nwg = nbx * gridDim.y;
  const int lsw = (lb & 7) * (nwg >> 3) + (lb >> 3);
  const int bm0 = (lsw / nbx) * 128;
  const int bn0 = (lsw % nbx) * 128;

  const int srow = lane >> 2;
  const int scol = ((lane & 3) ^ ((lane >> 3) & 3)) * 8;
  const int loff = l15 * 4 + (lhi ^ ((l15 >> 1) & 3));

  const int nkc = K >> 5;
  const bf16* bbase[4];
#pragma unroll
  for (int nt = 0; nt < 4; ++nt)
    bbase[nt] = Bft + ((size_t)((bn0 >> 4) + wng + nt) * nkc) * 512 + lane * 8;

  f32x4 acc[4][4];
  const f32x4 zero4 = {0.f, 0.f, 0.f, 0.f};
#pragma unroll
  for (int i = 0; i < 4; ++i)
#pragma unroll
    for (int j = 0; j < 4; ++j) acc[i][j] = zero4;

  short8 br0[4], br1[4], br2[4], br3[4];

#define GSTAGE_A(buf, kk)                                                          \
  { _Pragma("unroll")                                                              \
    for (int p = 0; p < 2; ++p) {                                                  \
      int s   = (p * 4 + w) * 64 + lane;                                           \
      int row = (p * 4 + w) * 16 + srow;                                           \
      GLOAD_LDS16(A + (size_t)(bm0 + row) * K + (kk) + scol, &As[buf][s * 8]);     \
    } }

#define BLOAD(breg, kc)                                                            \
  { _Pragma("unroll")                                                              \
    for (int nt = 0; nt < 4; ++nt) {                                               \
      asm volatile("global_load_dwordx4 %0, %1, off"                               \
                   : "=v"(breg[nt])                                                \
                   : "v"(bbase[nt] + (size_t)(kc) * 512)                           \
                   : "memory");                                                    \
    } }

#define KSTEP(aslot, breg, wcn, ...)                                               \
  {                                                                                \
    asm volatile("s_waitcnt vmcnt(" #wcn ")" ::: "memory");                        \
    __builtin_amdgcn_s_barrier();                                                  \
    __builtin_amdgcn_sched_barrier(0);                                             \
    __VA_ARGS__                                                                    \
    short8 a_[4];                                                                  \
    _Pragma("unroll")                                                              \
    for (int mt = 0; mt < 4; ++mt)                                                 \
      a_[mt] = *(const short8*)(&As[aslot][((wmg + mt) * 64 + loff) * 8]);         \
    _Pragma("unroll")                                                              \
    for (int mt = 0; mt < 4; ++mt)                                                 \
      _Pragma("unroll")                                                            \
      for (int nt = 0; nt < 4; ++nt)                                               \
        acc[mt][nt] = MFMA16(a_[mt], breg[nt], acc[mt][nt]);                       \
  }

  GSTAGE_A(0, 0);  BLOAD(br0, 0);
  GSTAGE_A(1, 32); BLOAD(br1, 1);
  GSTAGE_A(2, 64); BLOAD(br2, 2);

  for (int t = 0; t < nkc - 4; t += 4) {
    KSTEP(0, br0, 12, GSTAGE_A(3, (t + 3) * 32); BLOAD(br3, t + 3);)
    KSTEP(1, br1, 12, GSTAGE_A(0, (t + 4) * 32); BLOAD(br0, t + 4);)
    KSTEP(2, br2, 12, GSTAGE_A(1, (t + 5) * 32); BLOAD(br1, t + 5);)
    KSTEP(3, br3, 12, GSTAGE_A(2, (t + 6) * 32); BLOAD(br2, t + 6);)
  }
  KSTEP(0, br0, 12, GSTAGE_A(3, (nkc - 1) * 32); BLOAD(br3, nkc - 1);)
  KSTEP(1, br1, 12, )
  KSTEP(2, br2, 6, )
  KSTEP(3, br3, 0, )
#undef GSTAGE_A
#undef BLOAD
#undef KSTEP

#pragma unroll
  for (int mt = 0; mt < 4; ++mt) {
    int row0 = bm0 + (wmg + mt) * 16 + lhi * 4;
#pragma unroll
    for (int nt = 0; nt < 4; ++nt) {
      int col = bn0 + (wng + nt) * 16 + l15;
#pragma unroll
      for (int r = 0; r < 4; ++r)
        C[(size_t)(row0 + r) * N + col] = acc[mt][nt][r];
    }
  }
}

// ================= Differential attention: P-cached two-pass, LIFO pass-2 =================
// Pass 1: QK^T, fixed-base sums, store packed (e1,e2) per non-diagonal tile (ascending t).
// Pass 2: diagonal first (recompute), then t = qb-1 .. t0 DESCENDING so P reads hit the
// freshest L2 lines (LIFO locality on the 128KB/block P working set).
__global__ __launch_bounds__(256) void diff_attn(const bf16* __restrict__ QKV,
                                                 const bf16* __restrict__ VT,
                                                 const float* __restrict__ lam,
                                                 bf16* __restrict__ O,
                                                 unsigned* __restrict__ PA,
                                                 unsigned* __restrict__ PB)
{
  __shared__ __align__(16) bf16 Kb[2][64 * 128];
  __shared__ __align__(16) bf16 Vb[2][128 * 64];
  __shared__ __align__(16) bf16 Pw[4][16 * 72];

  const int lb  = blockIdx.y * 32 + blockIdx.x;
  const int lsw = (lb & 7) * 64 + (lb >> 3);
  const int qb  = lsw & 31;
  const int h   = lsw >> 5;

  const int kvh  = h >> 2;
  const int tid  = threadIdx.x;
  const int lane = tid & 63;
  const int w    = tid >> 6;
  const int l15  = lane & 15;
  const int lhi  = lane >> 4;
  const int qg   = qb * 64 + w * 16;
  const int myq  = qg + l15;
  const int qrow = w * 16 + l15;
  const float lamv = lam[h];

  unsigned* Pbase = (lsw < 160) ? (PA + (size_t)lsw * 32768)
                                : (PB + (size_t)(lsw - 160) * 32768);

  const bf16* Kg = QKV + 2048 + (size_t)kvh * 128;
  const bf16* Vg = VT + (size_t)kvh * 128 * 2048;

  short8 qf[4];
  {
    const bf16* qrowp = QKV + (size_t)myq * 3072 + h * 128;
#pragma unroll
    for (int c = 0; c < 4; ++c)
      qf[c] = *(const short8*)(qrowp + c * 32 + lhi * 8);
  }

  const int t0 = (qb >= 8) ? (qb - 8) : 0;

#define STAGE_K(buf, kbase)                                                     \
  {                                                                             \
    _Pragma("unroll")                                                           \
    for (int p = 0; p < 4; ++p) {                                               \
      int c = p * 256 + tid;                                                    \
      int r = c >> 4, q = c & 15;                                               \
      GLOAD_LDS16(Kg + (size_t)((kbase) + r) * 3072 + ((q ^ (r & 7)) * 8),      \
                  &Kb[buf][c * 8]);                                             \
    }                                                                           \
  }
#define STAGE_V(buf, kbase)                                                     \
  {                                                                             \
    _Pragma("unroll")                                                           \
    for (int p = 0; p < 4; ++p) {                                               \
      int c = p * 256 + tid;                                                    \
      int d = c >> 3, q = c & 7;                                                \
      GLOAD_LDS16(Vg + (size_t)d * 2048 + (kbase) + ((q ^ (d & 7)) * 8),        \
                  &Vb[buf][c * 8]);                                             \
    }                                                                           \
  }
#define KFRAG(buf, nt, qc) \
  (*(const short8*)(&Kb[buf][(((nt) * 16 + l15) * 16 + ((qc) ^ (((nt) * 16 + l15) & 7))) * 8]))
#define VFRAG(buf, n, qc) \
  (*(const short8*)(&Vb[buf][(((n) * 16 + l15) * 8 + ((qc) ^ (((n) * 16 + l15) & 7))) * 8]))
// s1 = permuted chunks 0,2 ; s2 = chunks 1,3 (bit5<->6 swapped layout)
#define QK_TILE(cur)                                            \
  _Pragma("unroll")                                             \
  for (int nt = 0; nt < 4; ++nt) {                              \
    f32x4 s1 = zero4, s2 = zero4;                               \
    s1 = MFMA16(KFRAG(cur, nt, lhi),      qf[0], s1);           \
    s1 = MFMA16(KFRAG(cur, nt, 8 + lhi),  qf[2], s1);           \
    s2 = MFMA16(KFRAG(cur, nt, 4 + lhi),  qf[1], s2);           \
    s2 = MFMA16(KFRAG(cur, nt, 12 + lhi), qf[3], s2);           \
    s1v[nt] = s1; s2v[nt] = s2;                                 \
  }

  const f32x4 zero4 = {0.f, 0.f, 0.f, 0.f};

  // ---------- pass 1 (ascending t, stores P) ----------
  float l1 = 0.f, l2 = 0.f;
  STAGE_K(0, t0 * 64);
  asm volatile("s_waitcnt vmcnt(0)" ::: "memory");
  __builtin_amdgcn_s_barrier();
  {
    int cur = 0;
    for (int t = t0; t <= qb; ++t, cur ^= 1) {
      if (t < qb) {
        STAGE_K(cur ^ 1, (t + 1) * 64);
        asm volatile("s_waitcnt vmcnt(4)" ::: "memory");
      } else {
        asm volatile("s_waitcnt vmcnt(0)" ::: "memory");
      }
      __builtin_amdgcn_s_barrier();
      __builtin_amdgcn_sched_barrier(0);
      const int kb0 = t * 64;
      f32x4 s1v[4], s2v[4];
      QK_TILE(cur);
      unsigned* Pt = Pbase + (size_t)(t - t0) * 4096;
      if (t == qb) {
        p1v<true, false>(s1v, s2v, l1, l2, kb0, myq, lhi, qrow, nullptr);
      } else if (qb >= 8 && t == t0) {
        p1v<true, true>(s1v, s2v, l1, l2, kb0, myq, lhi, qrow, Pt);
      } else {
        p1v<false, true>(s1v, s2v, l1, l2, kb0, myq, lhi, qrow, Pt);
      }
      __builtin_amdgcn_s_barrier();
    }
  }

  l1 += __shfl_xor(l1, 16, 64);
  l1 += __shfl_xor(l1, 32, 64);
  l2 += __shfl_xor(l2, 16, 64);
  l2 += __shfl_xor(l2, 32, 64);
  const float c2 = lamv * l1 / l2;

  // ---------- pass 2 (diagonal first, then LIFO over P tiles) ----------
  f32x4 accv[8];
#pragma unroll
  for (int n = 0; n < 8; ++n) accv[n] = zero4;
  float dln = 0.f;

  STAGE_V(0, qb * 64);
  STAGE_K(0, qb * 64);
  asm volatile("s_waitcnt vmcnt(0)" ::: "memory");
  __builtin_amdgcn_s_barrier();
  // prefetch first LIFO V tile while the diagonal computes
  if (qb > t0) STAGE_V(1, (qb - 1) * 64);
  {
    const int kb0 = qb * 64;
    unsigned* pw = (unsigned*)&Pw[w][0];
    f32x4 s1v[4], s2v[4];
    QK_TILE(0);
    dln += p2s<true>(s1v, s2v, c2, kb0, myq, lhi, l15, pw);
#pragma unroll
    for (int kc = 0; kc < 2; ++kc) {
      short8 pa2 = *(const short8*)(&Pw[w][l15 * 72 + kc * 32 + lhi * 8]);
#pragma unroll
      for (int n = 0; n < 8; ++n)
        accv[n] = MFMA16(pa2, VFRAG(0, n, kc * 4 + lhi), accv[n]);
    }
  }
  __builtin_amdgcn_s_barrier();   // all waves done with Vb[0] before it is restaged
  {
    int cur = 1;
    for (int t = qb - 1; t >= t0; --t, cur ^= 1) {
      // P loads first (freshest tiles first = LIFO L2 hits)
      const unsigned* Pt = Pbase + (size_t)(t - t0) * 4096 + qrow;
      unsigned pv[16];
#pragma unroll
      for (int kc = 0; kc < 2; ++kc)
#pragma unroll
        for (int j = 0; j < 8; ++j)
          pv[kc * 8 + j] = Pt[(kc * 32 + lhi * 8 + j) * 64];
      if (t > t0) {
        STAGE_V(cur ^ 1, (t - 1) * 64);
        asm volatile("s_waitcnt vmcnt(4)" ::: "memory");
      } else {
        asm volatile("s_waitcnt vmcnt(0)" ::: "memory");
      }
      __builtin_amdgcn_s_barrier();
      __builtin_amdgcn_sched_barrier(0);
      short8 pa[2];
      float dl = 0.f;
#pragma unroll
      for (int kc = 0; kc < 2; ++kc) {
        union { unsigned u[4]; short8 s; } pk;
#pragma unroll
        for (int jp = 0; jp < 4; ++jp) {
          unsigned a = pv[kc * 8 + 2 * jp];
          unsigned b = pv[kc * 8 + 2 * jp + 1];
          float p0 = fmaxf(fmaf(-c2, bfhi(a), bflo(a)), 0.f);
          float p1 = fmaxf(fmaf(-c2, bfhi(b), bflo(b)), 0.f);
          dl += p0 + p1;
          pk.u[jp] = packbf2(p0, p1);
        }
        pa[kc] = pk.s;
      }
      dln += dl;
#pragma unroll
      for (int kc = 0; kc < 2; ++kc)
#pragma unroll
        for (int n = 0; n < 8; ++n)
          accv[n] = MFMA16(pa[kc], VFRAG(cur, n, kc * 4 + lhi), accv[n]);
      __builtin_amdgcn_s_barrier();
    }
  }

  dln += __shfl_xor(dln, 16, 64);
  dln += __shfl_xor(dln, 32, 64);

#pragma unroll
  for (int r = 0; r < 4; ++r) {
    int srcq = lhi * 4 + r;
    int src = (lane & 48) | srcq;
    float dq = __shfl(dln, src, 64);
    float lq = __shfl(l1, src, 64);
    float rinv = 1.f / (dq + lq * 1e-6f);
    int qo = qg + srcq;
#pragma unroll
    for (int n = 0; n < 8; ++n) {
      O[(size_t)qo * 2048 + h * 128 + n * 16 + l15] =
          __float2bfloat16(accv[n][r] * rinv);
    }
  }
#undef STAGE_K
#undef STAGE_V
#undef KFRAG
#undef VFRAG
#undef QK_TILE
}

// ================= launch =================
extern "C" void kernel_launch(void* const* d_in, const int* in_sizes, int n_in,
                              void* d_out, int out_size, void* d_ws, size_t ws_size,
                              hipStream_t stream)
{
  const float* x   = (const float*)d_in[0];
  const float* Wq  = (const float*)d_in[1];
  const float* Wk  = (const float*)d_in[2];
  const float* Wv  = (const float*)d_in[3];
  const float* Wo  = (const float*)d_in[4];
  const float* lam = (const float*)d_in[5];

  char* ws = (char*)d_ws;
  bf16* xb     = (bf16*)(ws);                       // [2048][2048]  8 MB (dead after gemm_qkv)
  bf16* WqkvFT = (bf16*)(ws + 8ull  * (1u << 20));  // FT 3072x2048 12 MB (dead after gemm_qkv)
  bf16* WoFT   = (bf16*)(ws + 20ull * (1u << 20));  // FT 2048x2048  8 MB
  bf16* QKV    = (bf16*)(ws + 28ull * (1u << 20));  // [2048][3072] 12 MB
  bf16* ATT    = (bf16*)(ws + 40ull * (1u << 20));  // [2048][2048]  8 MB
  bf16* VT     = (bf16*)(ws + 48ull * (1u << 20));  // [512][2048]   2 MB
  unsigned* PA = (unsigned*)(ws);                   // P cache part A (reuses dead 0..20MB)
  unsigned* PB = (unsigned*)(ws + 50ull * (1u << 20)); // P cache part B (50..94MB)

  prep_all<<<dim3(144, 32), 256, 0, stream>>>(x, Wq, Wk, Wv, Wo, xb, WqkvFT, WoFT);
  gemm_qkv<<<dim3(16, 16), 512, 0, stream>>>(xb, WqkvFT, QKV, VT, 2048, 3072, 2048);
  diff_attn<<<dim3(32, 16), 256, 0, stream>>>(QKV, VT, lam, ATT, PA, PB);
  gemm_wo<<<dim3(16, 16), 256, 0, stream>>>(ATT, WoFT, (float*)d_out, 2048, 2048, 2048);
}

// Round 23
// 102.009 us; speedup vs baseline: 1.0096x; 1.0096x over previous
//
#include <hip/hip_runtime.h>
#include <hip/hip_bf16.h>
#include <stdint.h>

typedef __attribute__((ext_vector_type(8))) short short8;
typedef __attribute__((ext_vector_type(4))) float f32x4;
using bf16 = __hip_bfloat16;

#define MFMA16(a, b, c) __builtin_amdgcn_mfma_f32_16x16x32_bf16((a), (b), (c), 0, 0, 0)

#define GLOAD_LDS16(g, l) __builtin_amdgcn_global_load_lds( \
    (const __attribute__((address_space(1))) void*)(g),     \
    (__attribute__((address_space(3))) void*)(l), 16, 0, 0)

__device__ __forceinline__ unsigned packbf2(float lo, float hi) {
  unsigned r;
  asm("v_cvt_pk_bf16_f32 %0, %1, %2" : "=v"(r) : "v"(lo), "v"(hi));
  return r;
}
__device__ __forceinline__ float ex2(float x) {
  float r;
  asm("v_exp_f32 %0, %1" : "=v"(r) : "v"(x));
  return r;
}
__device__ __forceinline__ float bflo(unsigned a) {
  union { unsigned u; float f; } v; v.u = a << 16; return v.f;
}
__device__ __forceinline__ float bfhi(unsigned a) {
  union { unsigned u; float f; } v; v.u = a & 0xFFFF0000u; return v.f;
}

// pass-1: masked e1/e2, accumulate sums, optionally store packed (e1,e2) to P tile.
template <bool EDGE, bool STORE>
__device__ __forceinline__ void p1v(const f32x4* s1v, const f32x4* s2v,
                                    float& l1, float& l2,
                                    int kb0, int myq, int lhi, int qrow,
                                    unsigned* Pt) {
  float sum1 = 0.f, sum2 = 0.f;
#pragma unroll
  for (int nt = 0; nt < 4; ++nt) {
#pragma unroll
    for (int r = 0; r < 4; ++r) {
      float e1 = ex2(s1v[nt][r]);
      float e2 = ex2(s2v[nt][r]);
      if (EDGE) {
        int key = kb0 + nt * 16 + lhi * 4 + r;
        bool ok = (key <= myq) && (key > myq - 512);
        e1 = ok ? e1 : 0.f;
        e2 = ok ? e2 : 0.f;
      }
      sum1 += e1; sum2 += e2;
      if (STORE)
        Pt[(nt * 16 + lhi * 4 + r) * 64 + qrow] = packbf2(e1, e2);
    }
  }
  l1 += sum1; l2 += sum2;
}

// diagonal-tile pass-2 (recompute path)
template <bool EDGE>
__device__ __forceinline__ float p2s(const f32x4* s1v, const f32x4* s2v,
                                     float c2, int kb0, int myq, int lhi, int l15,
                                     unsigned* pw) {
  float d0 = 0.f, d1 = 0.f;
#pragma unroll
  for (int nt = 0; nt < 4; ++nt) {
    float pr[4];
#pragma unroll
    for (int r = 0; r < 4; ++r) {
      float e1 = ex2(s1v[nt][r]);
      float e2 = ex2(s2v[nt][r]);
      float p = fmaf(-c2, e2, e1);
      p = fmaxf(p, 0.f);
      if (EDGE) {
        int key = kb0 + nt * 16 + lhi * 4 + r;
        bool ok = (key <= myq) && (key > myq - 512);
        p = ok ? p : 0.f;
      }
      pr[r] = p;
      if (r & 1) d1 += p; else d0 += p;
    }
    int pi = l15 * 36 + 8 * nt + 2 * lhi;
    pw[pi]     = packbf2(pr[0], pr[1]);
    pw[pi + 1] = packbf2(pr[2], pr[3]);
  }
  return d0 + d1;
}

// ================= fused prep: x f32->bf16 row-major + weights -> FT bf16 =================
// Wq/Wk columns d-PERMUTED by swapping bits 5<->6 of d (self-inverse).
__global__ __launch_bounds__(256) void prep_all(const float* __restrict__ x,
                                                const float* __restrict__ Wq,
                                                const float* __restrict__ Wk,
                                                const float* __restrict__ Wv,
                                                const float* __restrict__ Wo,
                                                bf16* __restrict__ xb,
                                                bf16* __restrict__ WqkvFT,
                                                bf16* __restrict__ WoFT)
{
  const int bx = blockIdx.x;
  const int tid = threadIdx.x;
  if (bx >= 80) {
    size_t i = ((size_t)(bx - 80) * 32 + blockIdx.y) * 2048 + tid * 8;
    const float* f = x + i;
    float4 a = *(const float4*)f;
    float4 b = *(const float4*)(f + 4);
    union { bf16 h[8]; short8 s; } u;
    u.h[0] = __float2bfloat16(a.x); u.h[1] = __float2bfloat16(a.y);
    u.h[2] = __float2bfloat16(a.z); u.h[3] = __float2bfloat16(a.w);
    u.h[4] = __float2bfloat16(b.x); u.h[5] = __float2bfloat16(b.y);
    u.h[6] = __float2bfloat16(b.z); u.h[7] = __float2bfloat16(b.w);
    *(short8*)(xb + i) = u.s;
    return;
  }
  const float* W;
  bf16* Wt;
  int N, n0, prm;
  if (bx < 32)      { W = Wq; Wt = WqkvFT; N = 2048; n0 = bx * 64;               prm = 1; }
  else if (bx < 40) { W = Wk; Wt = WqkvFT; N = 512;  n0 = 2048 + (bx - 32) * 64; prm = 1; }
  else if (bx < 48) { W = Wv; Wt = WqkvFT; N = 512;  n0 = 2560 + (bx - 40) * 64; prm = 0; }
  else              { W = Wo; Wt = WoFT;   N = 2048; n0 = (bx - 48) * 64;        prm = 0; }
  const int nloc0 = (N == 512) ? (n0 - ((n0 >= 2560) ? 2560 : 2048)) : ((bx < 32 || bx >= 48) ? (n0 & 2047) : 0);
  const int k0 = blockIdx.y * 64;

  __shared__ bf16 t[64][72];
#pragma unroll
  for (int pass = 0; pass < 4; ++pass) {
    int r = pass * 16 + (tid >> 4);
    int c = (tid & 15) * 4;
    float4 v = *(const float4*)(W + (size_t)(k0 + r) * N + nloc0 + c);
    t[c + 0][r] = __float2bfloat16(v.x);
    t[c + 1][r] = __float2bfloat16(v.y);
    t[c + 2][r] = __float2bfloat16(v.z);
    t[c + 3][r] = __float2bfloat16(v.w);
  }
  __syncthreads();
#pragma unroll
  for (int pass = 0; pass < 2; ++pass) {
    int n = pass * 32 + (tid >> 3);
    int k8 = (tid & 7) * 8;
    int ng = n0 + n;
    if (prm) {
      int d = ng & 127;
      int dp = (d & 31) | ((d & 32) << 1) | ((d & 64) >> 1);
      ng = (ng & ~127) | dp;
    }
    int frag = (ng >> 4) * 64 + ((k0 + k8) >> 5);
    int ln = (ng & 15) + 16 * ((k8 >> 3) & 3);
    *(short8*)(Wt + (size_t)frag * 512 + ln * 8) = *(const short8*)(&t[n][k8]);
  }
}

// ================= QKV GEMM: 128x192 tile, 256 blocks, 8 waves (2m x 4n of 4x3) =================
__global__ __launch_bounds__(512) void gemm_qkv(const bf16* __restrict__ A,
                                                const bf16* __restrict__ Bft,
                                                bf16* __restrict__ QKV,
                                                bf16* __restrict__ VTp,
                                                int M, int N, int K)
{
  __shared__ __align__(16) char smem[65536];
  bf16* As = (bf16*)smem;

  const int tid  = threadIdx.x;
  const int lane = tid & 63;
  const int w    = tid >> 6;
  const int wmg  = (w >> 2) * 4;
  const int wn3  = (w & 3) * 3;
  const int l15  = lane & 15;
  const int lhi  = lane >> 4;

  const int nbx = gridDim.x;
  const int lb  = blockIdx.y * nbx + blockIdx.x;
  const int nwg = nbx * gridDim.y;
  const int lsw = (lb & 7) * (nwg >> 3) + (lb >> 3);
  const int bm0 = (lsw / nbx) * 128;
  const int bn0 = (lsw % nbx) * 192;

  const int srow = tid >> 2;
  const int scol = ((tid & 3) ^ ((tid >> 3) & 3)) * 8;
  const int loff = l15 * 4 + (lhi ^ ((l15 >> 1) & 3));

  const int nkc = K >> 5;
  const bf16* bbase[3];
#pragma unroll
  for (int nt = 0; nt < 3; ++nt)
    bbase[nt] = Bft + ((size_t)((bn0 >> 4) + wn3 + nt) * nkc) * 512 + lane * 8;

  f32x4 acc[4][3];
  const f32x4 zero4 = {0.f, 0.f, 0.f, 0.f};
#pragma unroll
  for (int i = 0; i < 4; ++i)
#pragma unroll
    for (int j = 0; j < 3; ++j) acc[i][j] = zero4;

  short8 br0[3], br1[3], br2[3], br3[3];

#define GSTAGE_A(buf, kk)                                                           \
  { GLOAD_LDS16(A + (size_t)(bm0 + srow) * K + (kk) + scol,                         \
                As + (buf) * 4096 + tid * 8); }

#define BLOAD(breg, kc)                                                             \
  { _Pragma("unroll")                                                               \
    for (int nt = 0; nt < 3; ++nt) {                                                \
      asm volatile("global_load_dwordx4 %0, %1, off"                                \
                   : "=v"(breg[nt])                                                 \
                   : "v"(bbase[nt] + (size_t)(kc) * 512)                            \
                   : "memory");                                                     \
    } }

#define KSTEP(aslot, breg, wcn, ...)                                                \
  {                                                                                 \
    asm volatile("s_waitcnt vmcnt(" #wcn ")" ::: "memory");                         \
    __builtin_amdgcn_s_barrier();                                                   \
    __builtin_amdgcn_sched_barrier(0);                                              \
    __VA_ARGS__                                                                     \
    short8 a_[4];                                                                   \
    _Pragma("unroll")                                                               \
    for (int mt = 0; mt < 4; ++mt)                                                  \
      a_[mt] = *(const short8*)(As + (aslot) * 4096 + ((wmg + mt) * 64 + loff) * 8);\
    _Pragma("unroll")                                                               \
    for (int mt = 0; mt < 4; ++mt)                                                  \
      _Pragma("unroll")                                                             \
      for (int nt = 0; nt < 3; ++nt)                                                \
        acc[mt][nt] = MFMA16(a_[mt], breg[nt], acc[mt][nt]);                        \
  }

  GSTAGE_A(0, 0);  BLOAD(br0, 0);
  GSTAGE_A(1, 32); BLOAD(br1, 1);
  GSTAGE_A(2, 64); BLOAD(br2, 2);

  for (int t = 0; t < nkc - 4; t += 4) {
    KSTEP(0, br0, 8, GSTAGE_A(3, (t + 3) * 32); BLOAD(br3, t + 3);)
    KSTEP(1, br1, 8, GSTAGE_A(0, (t + 4) * 32); BLOAD(br0, t + 4);)
    KSTEP(2, br2, 8, GSTAGE_A(1, (t + 5) * 32); BLOAD(br1, t + 5);)
    KSTEP(3, br3, 8, GSTAGE_A(2, (t + 6) * 32); BLOAD(br2, t + 6);)
  }
  KSTEP(0, br0, 8, GSTAGE_A(3, (nkc - 1) * 32); BLOAD(br3, nkc - 1);)
  KSTEP(1, br1, 8, )
  KSTEP(2, br2, 4, )
  KSTEP(3, br3, 0, )
#undef GSTAGE_A
#undef BLOAD
#undef KSTEP

  __syncthreads();

  const int ropeW = (bn0 + 192 <= 2560) ? 192 : ((bn0 >= 2560) ? 0 : 64);

  if (ropeW > 0) {
    float* Lf = (float*)smem;
#pragma unroll
    for (int half = 0; half < 2; ++half) {
      if ((w >> 2) == half) {
#pragma unroll
        for (int mt = 0; mt < 4; ++mt)
#pragma unroll
          for (int nt = 0; nt < 3; ++nt) {
            int lc = (wn3 + nt) * 16 + l15;
            if (lc < ropeW) {
#pragma unroll
              for (int r = 0; r < 4; ++r)
                Lf[(mt * 16 + lhi * 4 + r) * ropeW + lc] = acc[mt][nt][r];
            }
          }
      }
      __syncthreads();
      {
        int row = tid >> 3;
        int s = bm0 + half * 64 + row;
        if (ropeW == 192) {
          int cg = (tid & 7) * 24;
          bf16* orow = QKV + (size_t)s * 3072 + bn0 + cg;
          union { bf16 h[24]; short8 v[3]; } o;
#pragma unroll
          for (int e = 0; e < 24; ++e) {
            int c = cg + e;
            int g = bn0 + c;
            int p = g & 127;
            int w32 = p & 63;
            int b = p >> 6;
            int d = b * 32 + (w32 & 31);
            float scale = (g < 2048) ? 0.180336880111120f : 1.0f;
            float inv = __expf(-(float)d * (9.210340371976184f / 64.0f));
            float ang = (float)s * inv;
            float cs = __cosf(ang), sn = __sinf(ang);
            bool first = (w32 < 32);
            float xa = Lf[row * 192 + c];
            float xb2 = Lf[row * 192 + (first ? c + 32 : c - 32)];
            float out = fmaf(first ? -xb2 : xb2, sn, xa * cs);
            o.h[e] = __float2bfloat16(out * scale);
          }
          *(short8*)(orow)      = o.v[0];
          *(short8*)(orow + 8)  = o.v[1];
          *(short8*)(orow + 16) = o.v[2];
        } else {
          int cg = (tid & 7) * 8;
          bf16* orow = QKV + (size_t)s * 3072 + bn0 + cg;
          union { bf16 h[8]; short8 v; } o;
#pragma unroll
          for (int e = 0; e < 8; ++e) {
            int c = cg + e;
            int g = bn0 + c;
            int p = g & 127;
            int w32 = p & 63;
            int b = p >> 6;
            int d = b * 32 + (w32 & 31);
            float inv = __expf(-(float)d * (9.210340371976184f / 64.0f));
            float ang = (float)s * inv;
            float cs = __cosf(ang), sn = __sinf(ang);
            bool first = (w32 < 32);
            float xa = Lf[row * 64 + c];
            float xb2 = Lf[row * 64 + (first ? c + 32 : c - 32)];
            float out = fmaf(first ? -xb2 : xb2, sn, xa * cs);
            o.h[e] = __float2bfloat16(out);
          }
          *(short8*)(orow) = o.v;
        }
      }
      __syncthreads();
    }
  }
  if (bn0 + 192 > 2560) {
#pragma unroll
    for (int nt = 0; nt < 3; ++nt) {
      int gfc = bn0 + (wn3 + nt) * 16;
      if (gfc >= 2560) {
        int dim = gfc - 2560 + l15;
#pragma unroll
        for (int mt = 0; mt < 4; ++mt) {
          int key0 = bm0 + (w >> 2) * 64 + mt * 16 + lhi * 4;
          uint2 pk;
          pk.x = packbf2(acc[mt][nt][0], acc[mt][nt][1]);
          pk.y = packbf2(acc[mt][nt][2], acc[mt][nt][3]);
          *(uint2*)(VTp + (size_t)dim * 2048 + key0) = pk;
        }
      }
    }
  }
}

// ================= Wo GEMM: 128x128 tile, 512 threads (8 waves, 2m x 4n of 4x2) =================
// Ported to the QKV-proven 8-wave structure: 2 waves/SIMD hides VMEM under MFMA.
// A: 1 gload_lds/thread/K-step (same formula as QKV); B: 2 FT frags/wave direct-to-VGPR.
// Ring: 3 VMEM/thread/stage, counted vmcnt 6/6/3/0.
__global__ __launch_bounds__(512) void gemm_wo(const bf16* __restrict__ A,
                                               const bf16* __restrict__ Bft,
                                               float* __restrict__ C,
                                               int M, int N, int K)
{
  __shared__ __align__(16) bf16 As[4 * 4096];

  const int tid  = threadIdx.x;
  const int lane = tid & 63;
  const int w    = tid >> 6;          // 0..7
  const int wmg  = (w >> 2) * 4;      // m frag group: 0 or 4
  const int wn2  = (w & 3) * 2;       // n frag base: 0,2,4,6
  const int l15  = lane & 15;
  const int lhi  = lane >> 4;

  const int nbx = gridDim.x;          // 16
  const int lb  = blockIdx.y * nbx + blockIdx.x;
  const int nwg = nbx * gridDim.y;    // 256
  const int lsw = (lb & 7) * (nwg >> 3) + (lb >> 3);
  const int bm0 = (lsw / nbx) * 128;
  const int bn0 = (lsw % nbx) * 128;

  const int srow = tid >> 2;                              // 0..127
  const int scol = ((tid & 3) ^ ((tid >> 3) & 3)) * 8;
  const int loff = l15 * 4 + (lhi ^ ((l15 >> 1) & 3));

  const int nkc = K >> 5;
  const bf16* bbase[2];
#pragma unroll
  for (int nt = 0; nt < 2; ++nt)
    bbase[nt] = Bft + ((size_t)((bn0 >> 4) + wn2 + nt) * nkc) * 512 + lane * 8;

  f32x4 acc[4][2];
  const f32x4 zero4 = {0.f, 0.f, 0.f, 0.f};
#pragma unroll
  for (int i = 0; i < 4; ++i)
#pragma unroll
    for (int j = 0; j < 2; ++j) acc[i][j] = zero4;

  short8 br0[2], br1[2], br2[2], br3[2];

#define GSTAGE_A(buf, kk)                                                           \
  { GLOAD_LDS16(A + (size_t)(bm0 + srow) * K + (kk) + scol,                         \
                As + (buf) * 4096 + tid * 8); }

#define BLOAD(breg, kc)                                                             \
  { _Pragma("unroll")                                                               \
    for (int nt = 0; nt < 2; ++nt) {                                                \
      asm volatile("global_load_dwordx4 %0, %1, off"                                \
                   : "=v"(breg[nt])                                                 \
                   : "v"(bbase[nt] + (size_t)(kc) * 512)                            \
                   : "memory");                                                     \
    } }

#define KSTEP(aslot, breg, wcn, ...)                                                \
  {                                                                                 \
    asm volatile("s_waitcnt vmcnt(" #wcn ")" ::: "memory");                         \
    __builtin_amdgcn_s_barrier();                                                   \
    __builtin_amdgcn_sched_barrier(0);                                              \
    __VA_ARGS__                                                                     \
    short8 a_[4];                                                                   \
    _Pragma("unroll")                                                               \
    for (int mt = 0; mt < 4; ++mt)                                                  \
      a_[mt] = *(const short8*)(As + (aslot) * 4096 + ((wmg + mt) * 64 + loff) * 8);\
    _Pragma("unroll")                                                               \
    for (int mt = 0; mt < 4; ++mt)                                                  \
      _Pragma("unroll")                                                             \
      for (int nt = 0; nt < 2; ++nt)                                                \
        acc[mt][nt] = MFMA16(a_[mt], breg[nt], acc[mt][nt]);                        \
  }

  GSTAGE_A(0, 0);  BLOAD(br0, 0);
  GSTAGE_A(1, 32); BLOAD(br1, 1);
  GSTAGE_A(2, 64); BLOAD(br2, 2);

  for (int t = 0; t < nkc - 4; t += 4) {
    KSTEP(0, br0, 6, GSTAGE_A(3, (t + 3) * 32); BLOAD(br3, t + 3);)
    KSTEP(1, br1, 6, GSTAGE_A(0, (t + 4) * 32); BLOAD(br0, t + 4);)
    KSTEP(2, br2, 6, GSTAGE_A(1, (t + 5) * 32); BLOAD(br1, t + 5);)
    KSTEP(3, br3, 6, GSTAGE_A(2, (t + 6) * 32); BLOAD(br2, t + 6);)
  }
  KSTEP(0, br0, 6, GSTAGE_A(3, (nkc - 1) * 32); BLOAD(br3, nkc - 1);)
  KSTEP(1, br1, 6, )
  KSTEP(2, br2, 3, )
  KSTEP(3, br3, 0, )
#undef GSTAGE_A
#undef BLOAD
#undef KSTEP

#pragma unroll
  for (int mt = 0; mt < 4; ++mt) {
    int row0 = bm0 + (wmg + mt) * 16 + lhi * 4;
#pragma unroll
    for (int nt = 0; nt < 2; ++nt) {
      int col = bn0 + (w & 3) * 32 + nt * 16 + l15;
#pragma unroll
      for (int r = 0; r < 4; ++r)
        C[(size_t)(row0 + r) * N + col] = acc[mt][nt][r];
    }
  }
}

// ================= Differential attention: P-cached two-pass, LIFO pass-2 =================
__global__ __launch_bounds__(256) void diff_attn(const bf16* __restrict__ QKV,
                                                 const bf16* __restrict__ VT,
                                                 const float* __restrict__ lam,
                                                 bf16* __restrict__ O,
                                                 unsigned* __restrict__ PA,
                                                 unsigned* __restrict__ PB)
{
  __shared__ __align__(16) bf16 Kb[2][64 * 128];
  __shared__ __align__(16) bf16 Vb[2][128 * 64];
  __shared__ __align__(16) bf16 Pw[4][16 * 72];

  const int lb  = blockIdx.y * 32 + blockIdx.x;
  const int lsw = (lb & 7) * 64 + (lb >> 3);
  const int qb  = lsw & 31;
  const int h   = lsw >> 5;

  const int kvh  = h >> 2;
  const int tid  = threadIdx.x;
  const int lane = tid & 63;
  const int w    = tid >> 6;
  const int l15  = lane & 15;
  const int lhi  = lane >> 4;
  const int qg   = qb * 64 + w * 16;
  const int myq  = qg + l15;
  const int qrow = w * 16 + l15;
  const float lamv = lam[h];

  unsigned* Pbase = (lsw < 160) ? (PA + (size_t)lsw * 32768)
                                : (PB + (size_t)(lsw - 160) * 32768);

  const bf16* Kg = QKV + 2048 + (size_t)kvh * 128;
  const bf16* Vg = VT + (size_t)kvh * 128 * 2048;

  short8 qf[4];
  {
    const bf16* qrowp = QKV + (size_t)myq * 3072 + h * 128;
#pragma unroll
    for (int c = 0; c < 4; ++c)
      qf[c] = *(const short8*)(qrowp + c * 32 + lhi * 8);
  }

  const int t0 = (qb >= 8) ? (qb - 8) : 0;

#define STAGE_K(buf, kbase)                                                     \
  {                                                                             \
    _Pragma("unroll")                                                           \
    for (int p = 0; p < 4; ++p) {                                               \
      int c = p * 256 + tid;                                                    \
      int r = c >> 4, q = c & 15;                                               \
      GLOAD_LDS16(Kg + (size_t)((kbase) + r) * 3072 + ((q ^ (r & 7)) * 8),      \
                  &Kb[buf][c * 8]);                                             \
    }                                                                           \
  }
#define STAGE_V(buf, kbase)                                                     \
  {                                                                             \
    _Pragma("unroll")                                                           \
    for (int p = 0; p < 4; ++p) {                                               \
      int c = p * 256 + tid;                                                    \
      int d = c >> 3, q = c & 7;                                                \
      GLOAD_LDS16(Vg + (size_t)d * 2048 + (kbase) + ((q ^ (d & 7)) * 8),        \
                  &Vb[buf][c * 8]);                                             \
    }                                                                           \
  }
#define KFRAG(buf, nt, qc) \
  (*(const short8*)(&Kb[buf][(((nt) * 16 + l15) * 16 + ((qc) ^ (((nt) * 16 + l15) & 7))) * 8]))
#define VFRAG(buf, n, qc) \
  (*(const short8*)(&Vb[buf][(((n) * 16 + l15) * 8 + ((qc) ^ (((n) * 16 + l15) & 7))) * 8]))
#define QK_TILE(cur)                                            \
  _Pragma("unroll")                                             \
  for (int nt = 0; nt < 4; ++nt) {                              \
    f32x4 s1 = zero4, s2 = zero4;                               \
    s1 = MFMA16(KFRAG(cur, nt, lhi),      qf[0], s1);           \
    s1 = MFMA16(KFRAG(cur, nt, 8 + lhi),  qf[2], s1);           \
    s2 = MFMA16(KFRAG(cur, nt, 4 + lhi),  qf[1], s2);           \
    s2 = MFMA16(KFRAG(cur, nt, 12 + lhi), qf[3], s2);           \
    s1v[nt] = s1; s2v[nt] = s2;                                 \
  }

  const f32x4 zero4 = {0.f, 0.f, 0.f, 0.f};

  // ---------- pass 1 ----------
  float l1 = 0.f, l2 = 0.f;
  STAGE_K(0, t0 * 64);
  asm volatile("s_waitcnt vmcnt(0)" ::: "memory");
  __builtin_amdgcn_s_barrier();
  {
    int cur = 0;
    for (int t = t0; t <= qb; ++t, cur ^= 1) {
      if (t < qb) {
        STAGE_K(cur ^ 1, (t + 1) * 64);
        asm volatile("s_waitcnt vmcnt(4)" ::: "memory");
      } else {
        asm volatile("s_waitcnt vmcnt(0)" ::: "memory");
      }
      __builtin_amdgcn_s_barrier();
      __builtin_amdgcn_sched_barrier(0);
      const int kb0 = t * 64;
      f32x4 s1v[4], s2v[4];
      QK_TILE(cur);
      unsigned* Pt = Pbase + (size_t)(t - t0) * 4096;
      if (t == qb) {
        p1v<true, false>(s1v, s2v, l1, l2, kb0, myq, lhi, qrow, nullptr);
      } else if (qb >= 8 && t == t0) {
        p1v<true, true>(s1v, s2v, l1, l2, kb0, myq, lhi, qrow, Pt);
      } else {
        p1v<false, true>(s1v, s2v, l1, l2, kb0, myq, lhi, qrow, Pt);
      }
      __builtin_amdgcn_s_barrier();
    }
  }

  l1 += __shfl_xor(l1, 16, 64);
  l1 += __shfl_xor(l1, 32, 64);
  l2 += __shfl_xor(l2, 16, 64);
  l2 += __shfl_xor(l2, 32, 64);
  const float c2 = lamv * l1 / l2;

  // ---------- pass 2 (diagonal first, then LIFO over P tiles) ----------
  f32x4 accv[8];
#pragma unroll
  for (int n = 0; n < 8; ++n) accv[n] = zero4;
  float dln = 0.f;

  STAGE_V(0, qb * 64);
  STAGE_K(0, qb * 64);
  asm volatile("s_waitcnt vmcnt(0)" ::: "memory");
  __builtin_amdgcn_s_barrier();
  if (qb > t0) STAGE_V(1, (qb - 1) * 64);
  {
    const int kb0 = qb * 64;
    unsigned* pw = (unsigned*)&Pw[w][0];
    f32x4 s1v[4], s2v[4];
    QK_TILE(0);
    dln += p2s<true>(s1v, s2v, c2, kb0, myq, lhi, l15, pw);
#pragma unroll
    for (int kc = 0; kc < 2; ++kc) {
      short8 pa2 = *(const short8*)(&Pw[w][l15 * 72 + kc * 32 + lhi * 8]);
#pragma unroll
      for (int n = 0; n < 8; ++n)
        accv[n] = MFMA16(pa2, VFRAG(0, n, kc * 4 + lhi), accv[n]);
    }
  }
  __builtin_amdgcn_s_barrier();
  {
    int cur = 1;
    for (int t = qb - 1; t >= t0; --t, cur ^= 1) {
      const unsigned* Pt = Pbase + (size_t)(t - t0) * 4096 + qrow;
      unsigned pv[16];
#pragma unroll
      for (int kc = 0; kc < 2; ++kc)
#pragma unroll
        for (int j = 0; j < 8; ++j)
          pv[kc * 8 + j] = Pt[(kc * 32 + lhi * 8 + j) * 64];
      if (t > t0) {
        STAGE_V(cur ^ 1, (t - 1) * 64);
        asm volatile("s_waitcnt vmcnt(4)" ::: "memory");
      } else {
        asm volatile("s_waitcnt vmcnt(0)" ::: "memory");
      }
      __builtin_amdgcn_s_barrier();
      __builtin_amdgcn_sched_barrier(0);
      short8 pa[2];
      float dl = 0.f;
#pragma unroll
      for (int kc = 0; kc < 2; ++kc) {
        union { unsigned u[4]; short8 s; } pk;
#pragma unroll
        for (int jp = 0; jp < 4; ++jp) {
          unsigned a = pv[kc * 8 + 2 * jp];
          unsigned b = pv[kc * 8 + 2 * jp + 1];
          float p0 = fmaxf(fmaf(-c2, bfhi(a), bflo(a)), 0.f);
          float p1 = fmaxf(fmaf(-c2, bfhi(b), bflo(b)), 0.f);
          dl += p0 + p1;
          pk.u[jp] = packbf2(p0, p1);
        }
        pa[kc] = pk.s;
      }
      dln += dl;
#pragma unroll
      for (int kc = 0; kc < 2; ++kc)
#pragma unroll
        for (int n = 0; n < 8; ++n)
          accv[n] = MFMA16(pa[kc], VFRAG(cur, n, kc * 4 + lhi), accv[n]);
      __builtin_amdgcn_s_barrier();
    }
  }

  dln += __shfl_xor(dln, 16, 64);
  dln += __shfl_xor(dln, 32, 64);

#pragma unroll
  for (int r = 0; r < 4; ++r) {
    int srcq = lhi * 4 + r;
    int src = (lane & 48) | srcq;
    float dq = __shfl(dln, src, 64);
    float lq = __shfl(l1, src, 64);
    float rinv = 1.f / (dq + lq * 1e-6f);
    int qo = qg + srcq;
#pragma unroll
    for (int n = 0; n < 8; ++n) {
      O[(size_t)qo * 2048 + h * 128 + n * 16 + l15] =
          __float2bfloat16(accv[n][r] * rinv);
    }
  }
#undef STAGE_K
#undef STAGE_V
#undef KFRAG
#undef VFRAG
#undef QK_TILE
}

// ================= launch =================
extern "C" void kernel_launch(void* const* d_in, const int* in_sizes, int n_in,
                              void* d_out, int out_size, void* d_ws, size_t ws_size,
                              hipStream_t stream)
{
  const float* x   = (const float*)d_in[0];
  const float* Wq  = (const float*)d_in[1];
  const float* Wk  = (const float*)d_in[2];
  const float* Wv  = (const float*)d_in[3];
  const float* Wo  = (const float*)d_in[4];
  const float* lam = (const float*)d_in[5];

  char* ws = (char*)d_ws;
  bf16* xb     = (bf16*)(ws);                       // [2048][2048]  8 MB (dead after gemm_qkv)
  bf16* WqkvFT = (bf16*)(ws + 8ull  * (1u << 20));  // FT 3072x2048 12 MB (dead after gemm_qkv)
  bf16* WoFT   = (bf16*)(ws + 20ull * (1u << 20));  // FT 2048x2048  8 MB
  bf16* QKV    = (bf16*)(ws + 28ull * (1u << 20));  // [2048][3072] 12 MB
  bf16* ATT    = (bf16*)(ws + 40ull * (1u << 20));  // [2048][2048]  8 MB
  bf16* VT     = (bf16*)(ws + 48ull * (1u << 20));  // [512][2048]   2 MB
  unsigned* PA = (unsigned*)(ws);                   // P cache part A (reuses dead 0..20MB)
  unsigned* PB = (unsigned*)(ws + 50ull * (1u << 20)); // P cache part B (50..94MB)

  prep_all<<<dim3(144, 32), 256, 0, stream>>>(x, Wq, Wk, Wv, Wo, xb, WqkvFT, WoFT);
  gemm_qkv<<<dim3(16, 16), 512, 0, stream>>>(xb, WqkvFT, QKV, VT, 2048, 3072, 2048);
  diff_attn<<<dim3(32, 16), 256, 0, stream>>>(QKV, VT, lam, ATT, PA, PB);
  gemm_wo<<<dim3(16, 16), 512, 0, stream>>>(ATT, WoFT, (float*)d_out, 2048, 2048, 2048);
}